// Round 1
// baseline (368.663 us; speedup 1.0000x reference)
//
#include <hip/hip_runtime.h>

typedef __attribute__((ext_vector_type(8))) __bf16 bf16x8;
typedef __attribute__((ext_vector_type(4))) float f32x4;

#define GRID 1024
#define BLOCK 512
#define ITERS 8   // 4 batch rows per iter -> 32 rows per block

// swizzle for 128-col bf16 LDS tiles: spreads stride-256B row accesses across banks
__device__ __forceinline__ int swz(int row, int col) {
    return row * 128 + (col ^ ((row & 7) << 3));
}
// swizzle for 16-col bf16 LDS tiles
__device__ __forceinline__ int swz16(int row, int col) {
    return row * 16 + (col ^ ((row & 1) << 3));
}

__global__ __launch_bounds__(BLOCK, 2)
void fused_attn_kernel(const float* __restrict__ obs,
                       const float* __restrict__ W1, const float* __restrict__ b1,
                       const float* __restrict__ W2, const float* __restrict__ b2,
                       const float* __restrict__ W3, const float* __restrict__ b3,
                       const float* __restrict__ Uq, const float* __restrict__ Ur,
                       float* __restrict__ out)
{
    __shared__ __align__(16) __bf16 sW1[128 * 16];
    __shared__ __align__(16) __bf16 sW2[128 * 128];
    __shared__ __align__(16) __bf16 sW3[128 * 128];
    __shared__ __align__(16) __bf16 sX0[128 * 128];
    __shared__ __align__(16) __bf16 sX1[128 * 128];   // h2; later reused as UqT stage
    __shared__ __align__(16) __bf16 sA1[128 * 16];    // feats; later reused as query A (16x128)
    __shared__ float sMask[128];
    __shared__ float sB1[128], sB2[128], sB3[128];
    __shared__ float sQ2[4 * 128];
    __shared__ float sV[4 * 128];
    __shared__ float sWgt[128];
    __shared__ float sDen[4];

    const int tid = threadIdx.x;
    const int lane = tid & 63;
    const int wv = tid >> 6;      // wave 0..7
    const int wr = wv >> 1;       // 0..3 : 32-row group
    const int wc = wv & 1;        // 0..1 : 64-col group
    const int l15 = lane & 15;
    const int kh = lane >> 4;     // 0..3 : k-half selector

    // ---- stage weights once per block (bf16, swizzled) ----
    for (int i = tid; i < 128 * 16; i += BLOCK) {
        int r = i >> 4, c = i & 15;
        sW1[swz16(r, c)] = (__bf16)((c < 15) ? W1[r * 15 + c] : 0.f);
    }
    for (int i = tid; i < 128 * 128; i += BLOCK) {
        int r = i >> 7, c = i & 127;
        sW2[swz(r, c)] = (__bf16)W2[i];
        sW3[swz(r, c)] = (__bf16)W3[i];
    }
    if (tid < 128) { sB1[tid] = b1[tid]; sB2[tid] = b2[tid]; sB3[tid] = b3[tid]; }
    __syncthreads();

    for (int g = 0; g < ITERS; ++g) {
        const int row0 = blockIdx.x * (4 * ITERS) + g * 4;

        // ---- Phase B: stage feats (pad col15 to 0) + mask ----
        {
            int m = tid >> 2, f4 = tid & 3;
            int rb = row0 + (m >> 5), n = m & 31;
            f32x4 v = *(const f32x4*)&obs[rb * 576 + 32 + n * 16 + f4 * 4];
            if (f4 == 3) { sMask[m] = v.w; v.w = 0.f; }
            int c0 = f4 * 4;
            sA1[swz16(m, c0 + 0)] = (__bf16)v.x;
            sA1[swz16(m, c0 + 1)] = (__bf16)v.y;
            sA1[swz16(m, c0 + 2)] = (__bf16)v.z;
            sA1[swz16(m, c0 + 3)] = (__bf16)v.w;
        }
        __syncthreads();

        // ---- Layer 1: (128x16) @ (16x128), K padded to 32 with zero frags ----
        {
            f32x4 zero4 = {0.f, 0.f, 0.f, 0.f};
            f32x4 acc[2][4];
            #pragma unroll
            for (int mt = 0; mt < 2; ++mt)
                #pragma unroll
                for (int nt = 0; nt < 4; ++nt) acc[mt][nt] = zero4;

            bf16x8 zfrag;
            #pragma unroll
            for (int j = 0; j < 8; ++j) zfrag[j] = (__bf16)0.f;

            int c8 = (kh & 1) * 8;   // always-valid address; kh>=2 lanes discard
            bf16x8 af[2], bfr[4];
            #pragma unroll
            for (int mt = 0; mt < 2; ++mt) {
                int row = wr * 32 + mt * 16 + l15;
                bf16x8 t = *(const bf16x8*)&sA1[row * 16 + (c8 ^ ((row & 1) << 3))];
                af[mt] = (kh < 2) ? t : zfrag;
            }
            #pragma unroll
            for (int nt = 0; nt < 4; ++nt) {
                int col = wc * 64 + nt * 16 + l15;
                bf16x8 t = *(const bf16x8*)&sW1[col * 16 + (c8 ^ ((col & 1) << 3))];
                bfr[nt] = (kh < 2) ? t : zfrag;
            }
            #pragma unroll
            for (int mt = 0; mt < 2; ++mt)
                #pragma unroll
                for (int nt = 0; nt < 4; ++nt)
                    acc[mt][nt] = __builtin_amdgcn_mfma_f32_16x16x32_bf16(af[mt], bfr[nt], acc[mt][nt], 0, 0, 0);

            #pragma unroll
            for (int mt = 0; mt < 2; ++mt) {
                int rbase = wr * 32 + mt * 16 + kh * 4;
                #pragma unroll
                for (int nt = 0; nt < 4; ++nt) {
                    int col = wc * 64 + nt * 16 + l15;
                    float bb = sB1[col];
                    #pragma unroll
                    for (int r = 0; r < 4; ++r) {
                        float hv = fmaxf(acc[mt][nt][r] + bb, 0.f);
                        sX0[swz(rbase + r, col)] = (__bf16)hv;
                    }
                }
            }
        }
        __syncthreads();

        // ---- Layers 2 & 3: (128x128) @ (128x128) ----
        auto gemm128 = [&](const __bf16* A, const __bf16* Bw, const float* bias,
                           bool do_relu, bool do_mask, __bf16* Out) {
            f32x4 zero4 = {0.f, 0.f, 0.f, 0.f};
            f32x4 acc[2][4];
            #pragma unroll
            for (int mt = 0; mt < 2; ++mt)
                #pragma unroll
                for (int nt = 0; nt < 4; ++nt) acc[mt][nt] = zero4;

            #pragma unroll
            for (int kk = 0; kk < 4; ++kk) {
                int kb = kk * 32 + kh * 8;
                bf16x8 a[2], b[4];
                #pragma unroll
                for (int mt = 0; mt < 2; ++mt) {
                    int row = wr * 32 + mt * 16 + l15;
                    a[mt] = *(const bf16x8*)&A[row * 128 + (kb ^ ((row & 7) << 3))];
                }
                #pragma unroll
                for (int nt = 0; nt < 4; ++nt) {
                    int col = wc * 64 + nt * 16 + l15;
                    b[nt] = *(const bf16x8*)&Bw[col * 128 + (kb ^ ((col & 7) << 3))];
                }
                #pragma unroll
                for (int mt = 0; mt < 2; ++mt)
                    #pragma unroll
                    for (int nt = 0; nt < 4; ++nt)
                        acc[mt][nt] = __builtin_amdgcn_mfma_f32_16x16x32_bf16(a[mt], b[nt], acc[mt][nt], 0, 0, 0);
            }
            #pragma unroll
            for (int mt = 0; mt < 2; ++mt) {
                int rbase = wr * 32 + mt * 16 + kh * 4;
                #pragma unroll
                for (int nt = 0; nt < 4; ++nt) {
                    int col = wc * 64 + nt * 16 + l15;
                    float bb = bias[col];
                    #pragma unroll
                    for (int r = 0; r < 4; ++r) {
                        float hv = acc[mt][nt][r] + bb;
                        if (do_relu) hv = fmaxf(hv, 0.f);
                        if (do_mask) hv *= sMask[rbase + r];
                        Out[swz(rbase + r, col)] = (__bf16)hv;
                    }
                }
            }
        };
        gemm128(sX0, sW2, sB2, true, false, sX1);   // h2
        __syncthreads();
        gemm128(sX1, sW3, sB3, false, true, sX0);   // x_real (bf16) in sX0
        __syncthreads();

        // ---- Phase F: mask denom, raw query sums (-> sA1 as 16x128 A), stage UqT -> sX1 ----
        {
            if (tid < 128) {
                float mv = sMask[tid];
                #pragma unroll
                for (int off = 16; off > 0; off >>= 1) mv += __shfl_xor(mv, off, 32);
                if ((tid & 31) == 0) sDen[tid >> 5] = mv + 1e-5f;
            }
            int r = tid >> 7, e = tid & 127;
            float s = 0.f;
            #pragma unroll 8
            for (int i = 0; i < 32; ++i) s += (float)sX0[swz(r * 32 + i, e)];
            sA1[r * 128 + (e ^ (r << 3))] = (__bf16)s;   // r < 4 so (r&7)==r

            for (int i = tid; i < 128 * 128; i += BLOCK) {
                int er = i >> 7, d = i & 127;
                sX1[swz(d, er)] = (__bf16)Uq[i];          // UqT[d][e]
            }
        }
        __syncthreads();

        // ---- Phase G1: q = (query_raw @ UqT) / den via one padded-M MFMA GEMM ----
        {
            f32x4 acc = {0.f, 0.f, 0.f, 0.f};
            int nt = wv;                                   // wave -> 16-col slice
            #pragma unroll
            for (int kk = 0; kk < 4; ++kk) {
                int kb = kk * 32 + kh * 8;
                int arow = l15;                            // rows 0..3 valid, rest junk (finite)
                bf16x8 a = *(const bf16x8*)&sA1[arow * 128 + (kb ^ ((arow & 7) << 3))];
                int col = nt * 16 + l15;
                bf16x8 b = *(const bf16x8*)&sX1[col * 128 + (kb ^ ((col & 7) << 3))];
                acc = __builtin_amdgcn_mfma_f32_16x16x32_bf16(a, b, acc, 0, 0, 0);
            }
            if (kh == 0) {
                #pragma unroll
                for (int r = 0; r < 4; ++r)
                    sQ2[r * 128 + nt * 16 + l15] = acc[r] / sDen[r];
            }
        }
        __syncthreads();

        // ---- Phase G2: v[d] = sum_e Ur[e][d] * q[e]  (coalesced over d) ----
        {
            int r = tid >> 7, d = tid & 127;
            float a = 0.f;
            #pragma unroll 8
            for (int e = 0; e < 128; ++e)
                a += Ur[e * 128 + d] * sQ2[r * 128 + e];
            sV[r * 128 + d] = a;
        }
        __syncthreads();

        // ---- Phase H: logits + softmax over 32 objects ----
        if (tid < 128) {
            int m = tid, r = m >> 5;
            float a = 0.f;
            #pragma unroll
            for (int c8 = 0; c8 < 16; ++c8) {
                bf16x8 xv = *(const bf16x8*)&sX0[m * 128 + ((c8 * 8) ^ ((m & 7) << 3))];
                #pragma unroll
                for (int j = 0; j < 8; ++j)
                    a += (float)xv[j] * sV[r * 128 + c8 * 8 + j];
            }
            float logit = a + (1.0f - sMask[m]) * (-1e9f);
            float mx = logit;
            #pragma unroll
            for (int off = 16; off > 0; off >>= 1) mx = fmaxf(mx, __shfl_xor(mx, off, 32));
            float ex = __expf(logit - mx);
            float sm = ex;
            #pragma unroll
            for (int off = 16; off > 0; off >>= 1) sm += __shfl_xor(sm, off, 32);
            sWgt[m] = ex / sm;
        }
        __syncthreads();

        // ---- Phase I: out_att[e] = sum_n w[n] * x_real[n][e] ----
        {
            int r = tid >> 7, e = tid & 127;
            float a = 0.f;
            #pragma unroll 8
            for (int i = 0; i < 32; ++i)
                a += sWgt[r * 32 + i] * (float)sX0[swz(r * 32 + i, e)];
            out[(row0 + r) * 192 + 64 + e] = a;
        }
        // ---- Phase J: aux passthrough ----
        if (tid < 256) {
            int r = tid >> 6, j = tid & 63;
            out[(row0 + r) * 192 + j] = (j < 32) ? obs[(row0 + r) * 576 + j]
                                                 : obs[(row0 + r) * 576 + 512 + j];
        }
        __syncthreads();   // protect LDS reuse before next iteration
    }
}

extern "C" void kernel_launch(void* const* d_in, const int* in_sizes, int n_in,
                              void* d_out, int out_size, void* d_ws, size_t ws_size,
                              hipStream_t stream) {
    const float* obs = (const float*)d_in[0];
    const float* W1  = (const float*)d_in[1];
    const float* b1  = (const float*)d_in[2];
    const float* W2  = (const float*)d_in[3];
    const float* b2  = (const float*)d_in[4];
    const float* W3  = (const float*)d_in[5];
    const float* b3  = (const float*)d_in[6];
    const float* Uq  = (const float*)d_in[7];
    const float* Ur  = (const float*)d_in[8];
    float* out = (float*)d_out;

    fused_attn_kernel<<<dim3(GRID), dim3(BLOCK), 0, stream>>>(
        obs, W1, b1, W2, b2, W3, b3, Uq, Ur, out);
}